// Round 1
// baseline (265.744 us; speedup 1.0000x reference)
//
#include <hip/hip_runtime.h>
#include <stdint.h>

typedef unsigned int uint;
typedef unsigned short ushort;
typedef __attribute__((ext_vector_type(8))) short short8;
typedef __attribute__((ext_vector_type(16))) float floatx16;

#define MEG (1024u * 1024u)

// ---------- helpers ----------
__device__ inline ushort f2b(float f) {           // fp32 -> bf16 RNE
  union { float f; uint u; } c; c.f = f;
  uint u = c.u;
  u = (u + 0x7fffu + ((u >> 16) & 1u)) >> 16;
  return (ushort)u;
}
__device__ inline float b2f(ushort u) {
  union { uint i; float f; } c; c.i = ((uint)u) << 16; return c.f;
}

__device__ inline void gl_lds16(const ushort* g, ushort* l) {
  // async global->LDS, 16B/lane; LDS dest = wave-uniform base + lane*16
  __builtin_amdgcn_global_load_lds(
      (const __attribute__((address_space(1))) void*)g,
      (__attribute__((address_space(3))) void*)l, 16, 0, 0);
}

// raw barrier: NO implicit waitcnt drain (that drain was the 2-phase ceiling)
__device__ __forceinline__ void bar() {
  asm volatile("" ::: "memory");
  __builtin_amdgcn_s_barrier();
  asm volatile("" ::: "memory");
}
template <int N>
__device__ __forceinline__ void vm_wait() {
  asm volatile("s_waitcnt vmcnt(%0)" :: "n"(N) : "memory");
}
__device__ __forceinline__ void lgkm0() {
  asm volatile("s_waitcnt lgkmcnt(0)" ::: "memory");
}

// ---------------------------------------------------------------------------
// fp32->bf16 convert (x: 4096 blocks, W: 3x512 blocks) + Ls zeroing (1 block).
// ---------------------------------------------------------------------------
__global__ __launch_bounds__(256) void cvt_all(
    const float* __restrict__ x,  const float* __restrict__ wq,
    const float* __restrict__ wk, const float* __restrict__ wv,
    ushort* __restrict__ xb, ushort* __restrict__ wb,
    float* __restrict__ ls)
{
  const int b = blockIdx.x;
  if (b >= 5632) {                      // zero Lsum[4][2048]
    float4 z = make_float4(0.f, 0.f, 0.f, 0.f);
#pragma unroll
    for (int j = 0; j < 8; ++j)
      ((float4*)ls)[threadIdx.x * 8 + j] = z;
    return;
  }
  const float* s; ushort* d; int i;
  if (b < 4096) {
    s = x; d = xb; i = b * 256 + threadIdx.x;
  } else {
    int t = b - 4096;
    int wsel = t >> 9;
    s = (wsel == 0) ? wq : (wsel == 1) ? wk : wv;
    d = wb + (size_t)wsel * MEG;
    i = (t & 511) * 256 + threadIdx.x;
  }
  float4 a = ((const float4*)s)[i * 2];
  float4 c = ((const float4*)s)[i * 2 + 1];
  short8 v;
  v[0] = (short)f2b(a.x); v[1] = (short)f2b(a.y);
  v[2] = (short)f2b(a.z); v[3] = (short)f2b(a.w);
  v[4] = (short)f2b(c.x); v[5] = (short)f2b(c.y);
  v[6] = (short)f2b(c.z); v[7] = (short)f2b(c.w);
  ((short8*)d)[i] = v;
}

// ---------------------------------------------------------------------------
// R12: T3+T4+T5 restructure (8-phase-class schedule, plain HIP).
//   BM=256, BK=32, 4-slot LDS ring, 512 thr = 8 waves.
//   BN=256 (QKV,S): waves 2Mx4N, per-wave 128x64, acc[4][2] floatx16.
//   BN=128 (PV):    waves 4Mx2N, per-wave  64x64, acc[2][2].
//   Per K-tile: 1-2 phases of {ds_read subtile | stage t+3 | bar | lgkm0 |
//   setprio(1) 8xMFMA setprio(0) | bar}; counted vmcnt (8/6 steady, never 0
//   in main loop), staging 3 K-tiles ahead in the ring.
//   Race-freedom: slot(t+3)==slot(t-1); t-1's ds_reads all retired (per-wave
//   lgkmcnt(0)) before its final barrier, and t+3's stage issues after that
//   barrier. RAW: vmcnt(2*LPT)+barrier at end of tile t guarantees tile t+1's
//   loads (issued at t-2) are complete in every wave before t+1's ds_reads.
//   Swizzle: 2-bit XOR on 16B chunks within 64B rows, pre-applied on the
//   GLOBAL source (gl_lds dest stays linear, rule 21), undone on ds_read.
//   MODE 0: fused-QKV split epilogue; MODE 1: p=exp2(s*scale)+Lsum atomics;
//   MODE 2: fp32 out * 1/Lsum[row].
// ---------------------------------------------------------------------------
template <int MODE, int BN>
__device__ __forceinline__ void gemm_core(
    const ushort* __restrict__ A, int lda, size_t sA,
    const ushort* __restrict__ B, int ldb, size_t sB,
    void* __restrict__ C, int ldc, size_t sC,
    int K, float scale, float* __restrict__ Lsum)
{
  static_assert(BN == 256 || BN == 128, "BN");
  constexpr int BM = 256;
  constexpr int BK = 32;
  constexpr int WAVES_M = (BN == 256) ? 2 : 4;
  constexpr int WAVES_N = 8 / WAVES_M;
  constexpr int MI = BM / (WAVES_M * 32);   // 4 (BN=256) or 2 (BN=128)
  constexpr int NJ = BN / (WAVES_N * 32);   // 2
  constexpr int A_ISS = BM / 128;           // 2
  constexpr int B_ISS = BN / 128;           // 2 or 1
  constexpr int LPT = A_ISS + B_ISS;        // gl_lds per thread per K-tile

  __shared__ ushort As[4 * BM * BK];        // 64 KiB
  __shared__ ushort Bs[4 * BN * BK];        // 64 / 32 KiB

  const int tid = threadIdx.x;
  const int bz  = blockIdx.z;
  A += (size_t)bz * sA;
  B += (size_t)bz * sB;

  const int m0 = blockIdx.y * BM;
  const int n0 = blockIdx.x * BN;

  const int lane = tid & 63;
  const int w    = tid >> 6;
  const int l32  = lane & 31;
  const int lh   = lane >> 5;
  const int mw   = (BN == 256) ? (w >> 2) : (w >> 1);
  const int nw   = (BN == 256) ? (w & 3) : (w & 1);

  // ---- staging pointers: 128 rows/issue, 4 lanes x 16B per 64B row ----
  const int srow = tid >> 2;                // 0..127
  const int sch  = tid & 3;
  const ushort* agp[A_ISS];
  const ushort* bgp[B_ISS];
#pragma unroll
  for (int q = 0; q < A_ISS; ++q) {
    int r = q * 128 + srow;
    agp[q] = A + (size_t)(m0 + r) * lda + ((sch ^ ((r ^ (r >> 3)) & 3)) * 8);
  }
#pragma unroll
  for (int q = 0; q < B_ISS; ++q) {
    int r = q * 128 + srow;
    bgp[q] = B + (size_t)(n0 + r) * ldb + ((sch ^ ((r ^ (r >> 3)) & 3)) * 8);
  }

  // ---- fragment read offsets + swizzle keys (loop-invariant) ----
  int oa[MI], sa[MI], ob[NJ], sb[NJ];
#pragma unroll
  for (int i = 0; i < MI; ++i) {
    int r = mw * (MI * 32) + i * 32 + l32;
    oa[i] = r * BK; sa[i] = (r ^ (r >> 3)) & 3;
  }
#pragma unroll
  for (int j = 0; j < NJ; ++j) {
    int r = nw * (NJ * 32) + j * 32 + l32;
    ob[j] = r * BK; sb[j] = (r ^ (r >> 3)) & 3;
  }

  floatx16 acc[MI][NJ];
#pragma unroll
  for (int i = 0; i < MI; ++i)
#pragma unroll
    for (int j = 0; j < NJ; ++j)
#pragma unroll
      for (int r = 0; r < 16; ++r) acc[i][j][r] = 0.f;

  const int nt = K / BK;

  // ---- prologue: stage K-tiles 0,1,2 into slots 0,1,2 ----
#pragma unroll
  for (int pt = 0; pt < 3; ++pt) {
    ushort* Ad = &As[pt * (BM * BK)];
    ushort* Bd = &Bs[pt * (BN * BK)];
#pragma unroll
    for (int q = 0; q < A_ISS; ++q) {
      gl_lds16(agp[q], Ad + (q * 128 + w * 16) * BK); agp[q] += BK;
    }
#pragma unroll
    for (int q = 0; q < B_ISS; ++q) {
      gl_lds16(bgp[q], Bd + (q * 128 + w * 16) * BK); bgp[q] += BK;
    }
  }
  vm_wait<2 * LPT>();     // tile 0 resident; tiles 1,2 in flight
  bar();

  // ---- main K-loop ----
  for (int t = 0; t < nt; ++t) {
    const ushort* At = &As[(t & 3) * (BM * BK)];
    const ushort* Bt = &Bs[(t & 3) * (BN * BK)];
    ushort* Ad = &As[((t + 3) & 3) * (BM * BK)];
    ushort* Bd = &Bs[((t + 3) & 3) * (BN * BK)];
    const bool st = (t + 3 < nt);

    // B fragments: loaded once, live across both phases
    short8 bf[NJ][2];
#pragma unroll
    for (int j = 0; j < NJ; ++j)
#pragma unroll
      for (int ks = 0; ks < 2; ++ks)
        bf[j][ks] = *(const short8*)(Bt + ob[j] + ((((ks * 2) + lh) ^ sb[j]) << 3));

    short8 af[2][2];
    // ---- phase 0: frag-rows 0,1 ----
#pragma unroll
    for (int i = 0; i < 2; ++i)
#pragma unroll
      for (int ks = 0; ks < 2; ++ks)
        af[i][ks] = *(const short8*)(At + oa[i] + ((((ks * 2) + lh) ^ sa[i]) << 3));
    if (st) {
#pragma unroll
      for (int q = 0; q < A_ISS; ++q) {
        gl_lds16(agp[q], Ad + (q * 128 + w * 16) * BK); agp[q] += BK;
      }
      if constexpr (BN == 128) {
#pragma unroll
        for (int q = 0; q < B_ISS; ++q) {
          gl_lds16(bgp[q], Bd + (q * 128 + w * 16) * BK); bgp[q] += BK;
        }
      }
    }
    bar();
    lgkm0();
    __builtin_amdgcn_s_setprio(1);
#pragma unroll
    for (int i = 0; i < 2; ++i)
#pragma unroll
      for (int j = 0; j < NJ; ++j)
#pragma unroll
        for (int ks = 0; ks < 2; ++ks)
          acc[i][j] = __builtin_amdgcn_mfma_f32_32x32x16_bf16(
              af[i][ks], bf[j][ks], acc[i][j], 0, 0, 0);
    __builtin_amdgcn_s_setprio(0);
    if constexpr (BN == 128) {     // single-phase tile: vmcnt ladder here
      if (t + 3 < nt)      vm_wait<2 * LPT>();
      else if (t + 2 < nt) vm_wait<LPT>();
      else                 vm_wait<0>();
    }
    bar();

    if constexpr (BN == 256) {
      // ---- phase 1: frag-rows 2,3 ----
#pragma unroll
      for (int i = 0; i < 2; ++i)
#pragma unroll
        for (int ks = 0; ks < 2; ++ks)
          af[i][ks] = *(const short8*)(At + oa[2 + i] + ((((ks * 2) + lh) ^ sa[2 + i]) << 3));
      if (st) {
#pragma unroll
        for (int q = 0; q < B_ISS; ++q) {
          gl_lds16(bgp[q], Bd + (q * 128 + w * 16) * BK); bgp[q] += BK;
        }
      }
      bar();
      lgkm0();
      __builtin_amdgcn_s_setprio(1);
#pragma unroll
      for (int i = 0; i < 2; ++i)
#pragma unroll
        for (int j = 0; j < NJ; ++j)
#pragma unroll
          for (int ks = 0; ks < 2; ++ks)
            acc[2 + i][j] = __builtin_amdgcn_mfma_f32_32x32x16_bf16(
                af[i][ks], bf[j][ks], acc[2 + i][j], 0, 0, 0);
      __builtin_amdgcn_s_setprio(0);
      if (t + 3 < nt)      vm_wait<2 * LPT>();   // tiles t+2,t+3 in flight
      else if (t + 2 < nt) vm_wait<LPT>();       // only t+2 in flight
      else                 vm_wait<0>();         // epilogue drain
      bar();
    }
  }

  // ---- epilogue; C/D (32x32): col = lane&31, row = (reg&3)+8*(reg>>2)+4*lh
  if constexpr (MODE == 0) {   // fused-QKV split
#pragma unroll
    for (int i = 0; i < MI; ++i)
#pragma unroll
      for (int j = 0; j < NJ; ++j) {
        const int mbase = m0 + mw * (MI * 32) + i * 32 + 4 * lh;
        const int ng    = n0 + nw * (NJ * 32) + j * 32 + l32;
        if (ng < 2048) {
          // Qb @ C, Kb @ C + 8M elems
          ushort* dst = (ushort*)C + (size_t)(ng >> 10) * (8u * MEG);
          const int nn = ng & 1023;
#pragma unroll
          for (int g = 0; g < 4; ++g)
#pragma unroll
            for (int r = 0; r < 4; ++r)
              dst[(size_t)(mbase + 8 * g + r) * 1024 + nn] =
                  f2b(acc[i][j][4 * g + r]);
        } else {
          // Vt @ C + 16M elems, transposed [1024][8192]
          ushort* Vo = (ushort*)C + (size_t)16 * MEG;
#pragma unroll
          for (int g = 0; g < 4; ++g) {
            uint lo = (uint)f2b(acc[i][j][4 * g + 0]) |
                      ((uint)f2b(acc[i][j][4 * g + 1]) << 16);
            uint hi = (uint)f2b(acc[i][j][4 * g + 2]) |
                      ((uint)f2b(acc[i][j][4 * g + 3]) << 16);
            *(uint2*)&Vo[(size_t)(ng - 2048) * 8192 + mbase + 8 * g] =
                make_uint2(lo, hi);
          }
        }
      }
  } else if constexpr (MODE == 1) {   // p = exp2(s*scale), row sums -> Lsum
    ushort* Cb = (ushort*)C + (size_t)bz * sC;
    float* Lb = Lsum + (size_t)bz * 2048;
    const int ng0 = n0 + nw * (NJ * 32) + l32;
#pragma unroll
    for (int i = 0; i < MI; ++i) {
      const int mbase = m0 + mw * (MI * 32) + i * 32 + 4 * lh;
#pragma unroll
      for (int g = 0; g < 4; ++g)
#pragma unroll
        for (int r = 0; r < 4; ++r) {
          const int mg = mbase + 8 * g + r;
          float p0 = exp2f(acc[i][0][4 * g + r] * scale);
          float p1 = exp2f(acc[i][NJ - 1][4 * g + r] * scale);
          ushort u0 = f2b(p0), u1 = f2b(p1);
          Cb[(size_t)mg * ldc + ng0]      = u0;
          Cb[(size_t)mg * ldc + ng0 + 32] = u1;
          float ps = b2f(u0) + b2f(u1);   // sum of *rounded* p (matches PV)
#pragma unroll
          for (int d = 1; d < 32; d <<= 1) ps += __shfl_xor(ps, d);
          if (l32 == 0) atomicAdd(&Lb[mg], ps);
        }
    }
  } else {                    // MODE 2: normalized fp32 output
    float* Cb = (float*)C + (size_t)bz * sC;
    const float* Lb = Lsum + (size_t)bz * 2048;
#pragma unroll
    for (int i = 0; i < MI; ++i) {
      const int mbase = m0 + mw * (MI * 32) + i * 32 + 4 * lh;
#pragma unroll
      for (int g = 0; g < 4; ++g)
#pragma unroll
        for (int r = 0; r < 4; ++r) {
          const int mg = mbase + 8 * g + r;
          const float inv = 1.0f / Lb[mg];
#pragma unroll
          for (int j = 0; j < NJ; ++j) {
            const int ng = n0 + nw * (NJ * 32) + j * 32 + l32;
            Cb[(size_t)mg * ldc + ng] = acc[i][j][4 * g + r] * inv;
          }
        }
    }
  }
}

// ---- distinct symbols per stage (counter attribution) ----
// (512,2): cap VGPR at 256 so all 8 waves of the single resident block fit
// 2 waves/SIMD. 1 block/CU by LDS (128 KiB); pipeline, not TLP, hides latency.
__global__ __launch_bounds__(512, 2) void gemm_qkv(
    const ushort* __restrict__ A, int lda, size_t sA,
    const ushort* __restrict__ B, int ldb, size_t sB,
    void* __restrict__ C, int ldc, size_t sC, int K, float scale,
    float* __restrict__ Lsum) {
  gemm_core<0, 256>(A, lda, sA, B, ldb, sB, C, ldc, sC, K, scale, Lsum);
}
__global__ __launch_bounds__(512, 2) void gemm_s(
    const ushort* __restrict__ A, int lda, size_t sA,
    const ushort* __restrict__ B, int ldb, size_t sB,
    void* __restrict__ C, int ldc, size_t sC, int K, float scale,
    float* __restrict__ Lsum) {
  gemm_core<1, 256>(A, lda, sA, B, ldb, sB, C, ldc, sC, K, scale, Lsum);
}
__global__ __launch_bounds__(512, 2) void gemm_pv(
    const ushort* __restrict__ A, int lda, size_t sA,
    const ushort* __restrict__ B, int ldb, size_t sB,
    void* __restrict__ C, int ldc, size_t sC, int K, float scale,
    float* __restrict__ Lsum) {
  gemm_core<2, 128>(A, lda, sA, B, ldb, sB, C, ldc, sC, K, scale, Lsum);
}

// ---------------------------------------------------------------------------
// ws layout (ushort elems), total 80 MiB + 32 KiB  (proven ws >= 90.2 MB):
//   Qb @ 0      [8192][1024]   (16 MiB)
//   Kb @ 8M     [8192][1024]   (16 MiB)
//   Vt @ 16M    [1024][8192]   (16 MiB)
//   xb @ 24M    [8192][1024]   (16 MiB)  -- dead after QKV
//   Wb @ 32M    [3072][1024]   ( 6 MiB)  -- dead after QKV
//   P  @ 24M    [4][2048][2048] (32 MiB) -- OVERLAYS xb+Wb (both dead)
//   Ls @ 40M    fp32 [4][2048]  (32 KiB)
// Grids (256-wide tiles): QKV 12x32=384 blk (1.5 rounds), S 8x8x4=256 blk
// (exactly 1 round), PV 8x8x4=256 blk (exactly 1 round).
// ---------------------------------------------------------------------------
extern "C" void kernel_launch(void* const* d_in, const int* in_sizes, int n_in,
                              void* d_out, int out_size, void* d_ws, size_t ws_size,
                              hipStream_t stream) {
  const float* x  = (const float*)d_in[0];
  const float* Wq = (const float*)d_in[1];
  const float* Wk = (const float*)d_in[2];
  const float* Wv = (const float*)d_in[3];
  float* outp = (float*)d_out;

  const float SCALE = 1.4426950408889634f / 32.0f;   // log2(e)/sqrt(1024)

  ushort* W0 = (ushort*)d_ws;
  ushort* Qb = W0;
  ushort* Kb = W0 + (size_t)8 * MEG;
  ushort* Vt = W0 + (size_t)16 * MEG;
  ushort* xb = W0 + (size_t)24 * MEG;
  ushort* Wb = W0 + (size_t)32 * MEG;
  ushort* Pb = W0 + (size_t)24 * MEG;            // overlays xb/Wb after QKV

  const size_t NEED_FULL = ((size_t)40 * MEG) * 2 + 4 * 2048 * 4;  // 83,918,848
  const bool full = ws_size >= NEED_FULL;
  float* Ls = full ? (float*)(W0 + (size_t)40 * MEG)
                   : (float*)(W0 + (size_t)28 * MEG);  // per-batch: P is 8 MiB

  cvt_all<<<5633, 256, 0, stream>>>(x, Wq, Wk, Wv, xb, Wb, Ls);

  // fused QKV projection: [8192x1024] x [3072x1024]^T, split epilogue
  gemm_qkv<<<dim3(12, 32, 1), 512, 0, stream>>>(
      xb, 1024, 0, Wb, 1024, 0, Qb, 1024, 0, 1024, 1.f, nullptr);

  if (full) {
    gemm_s<<<dim3(8, 8, 4), 512, 0, stream>>>(
        Qb, 1024, (size_t)2048 * 1024, Kb, 1024, (size_t)2048 * 1024,
        Pb, 2048, (size_t)2048 * 2048, 1024, SCALE, Ls);
    gemm_pv<<<dim3(8, 8, 4), 512, 0, stream>>>(
        Pb, 2048, (size_t)2048 * 2048, Vt, 8192, 2048,
        outp, 1024, (size_t)2048 * 1024, 2048, 1.f, Ls);
  } else {
    // per-batch fallback (P single batch @24M, Ls @28M)
    for (int b = 0; b < 4; ++b) {
      (void)hipMemsetAsync(Ls, 0, 2048 * sizeof(float), stream);
      gemm_s<<<dim3(8, 8, 1), 512, 0, stream>>>(
          Qb + (size_t)b * 2048 * 1024, 1024, 0,
          Kb + (size_t)b * 2048 * 1024, 1024, 0,
          Pb, 2048, 0, 1024, SCALE, Ls);
      gemm_pv<<<dim3(8, 8, 1), 512, 0, stream>>>(
          Pb, 2048, 0, Vt + (size_t)b * 2048, 8192, 0,
          outp + (size_t)b * 2048 * 1024, 1024, 0, 2048, 1.f, Ls);
    }
  }
}

// Round 2
// 262.824 us; speedup vs baseline: 1.0111x; 1.0111x over previous
//
#include <hip/hip_runtime.h>
#include <stdint.h>

typedef unsigned int uint;
typedef unsigned short ushort;
typedef __attribute__((ext_vector_type(8))) short short8;
typedef __attribute__((ext_vector_type(16))) float floatx16;

#define MEG (1024u * 1024u)

// ---------- helpers ----------
__device__ inline ushort f2b(float f) {           // fp32 -> bf16 RNE
  union { float f; uint u; } c; c.f = f;
  uint u = c.u;
  u = (u + 0x7fffu + ((u >> 16) & 1u)) >> 16;
  return (ushort)u;
}
__device__ inline float b2f(ushort u) {
  union { uint i; float f; } c; c.i = ((uint)u) << 16; return c.f;
}

__device__ inline void gl_lds16(const ushort* g, ushort* l) {
  // async global->LDS, 16B/lane; LDS dest = wave-uniform base + lane*16
  __builtin_amdgcn_global_load_lds(
      (const __attribute__((address_space(1))) void*)g,
      (__attribute__((address_space(3))) void*)l, 16, 0, 0);
}

// ---------------------------------------------------------------------------
// fp32->bf16 convert (x: 4096 blocks, W: 3x512 blocks) + Ls zeroing (1 block).
// ---------------------------------------------------------------------------
__global__ __launch_bounds__(256) void cvt_all(
    const float* __restrict__ x,  const float* __restrict__ wq,
    const float* __restrict__ wk, const float* __restrict__ wv,
    ushort* __restrict__ xb, ushort* __restrict__ wb,
    float* __restrict__ ls)
{
  const int b = blockIdx.x;
  if (b >= 5632) {                      // zero Lsum[4][2048]
    float4 z = make_float4(0.f, 0.f, 0.f, 0.f);
#pragma unroll
    for (int j = 0; j < 8; ++j)
      ((float4*)ls)[threadIdx.x * 8 + j] = z;
    return;
  }
  const float* s; ushort* d; int i;
  if (b < 4096) {
    s = x; d = xb; i = b * 256 + threadIdx.x;
  } else {
    int t = b - 4096;
    int wsel = t >> 9;
    s = (wsel == 0) ? wq : (wsel == 1) ? wk : wv;
    d = wb + (size_t)wsel * MEG;
    i = (t & 511) * 256 + threadIdx.x;
  }
  float4 a = ((const float4*)s)[i * 2];
  float4 c = ((const float4*)s)[i * 2 + 1];
  short8 v;
  v[0] = (short)f2b(a.x); v[1] = (short)f2b(a.y);
  v[2] = (short)f2b(a.z); v[3] = (short)f2b(a.w);
  v[4] = (short)f2b(c.x); v[5] = (short)f2b(c.y);
  v[6] = (short)f2b(c.z); v[7] = (short)f2b(c.w);
  ((short8*)d)[i] = v;
}

// ---------------------------------------------------------------------------
// R13: free-flow double-buffered core. BM=256, BK=64, 512 thr = 8 waves.
//   ONE __syncthreads per K-tile (R12's 4 barriers/tile serialized the LDS
//   and MFMA pipes: 1600cyc phases for 512cyc of MFMA). Stage of tile t+1
//   issues at the TOP of tile t -> the barrier's implicit vmcnt(0) drain
//   waits on ~2000-cycle-old loads (free), unlike R0 where issue->drain was
//   adjacent (full HBM latency exposed per tile).
//   Within a tile: k-slice read-ahead in program order; compiler emits
//   counted lgkmcnt (m97-style), waves free-flow between barriers so LDS
//   reads of one wave overlap MFMA of another. setprio(1) around each
//   8-MFMA cluster (T5: role diversity now exists).
//   Race-freedom: slot s^1 is written (gl_lds) only during tile t; it was
//   last read by tile t-1, whose reads drained before t's opening barrier;
//   it is next read by tile t+1, after the closing barrier+vmcnt(0) drain.
//   Swizzle: 3-bit XOR on 16B chunks within 128B rows, pre-applied on the
//   GLOBAL source (gl_lds dest stays linear, rule 21), undone on ds_read.
//   Proven in R0/R5: SQ_LDS_BANK_CONFLICT == 0.
//   BN=256 (QKV,S): waves 2Mx4N, per-wave 128x64, acc[4][2] floatx16.
//   BN=128 (PV):    waves 4Mx2N, per-wave  64x64, acc[2][2].
//   MODE 0: fused-QKV split epilogue; MODE 1: p=exp2(s*scale)+Lsum atomics;
//   MODE 2: fp32 out * 1/Lsum[row].
// ---------------------------------------------------------------------------
template <int MODE, int BN>
__device__ __forceinline__ void gemm_core(
    const ushort* __restrict__ A, int lda, size_t sA,
    const ushort* __restrict__ B, int ldb, size_t sB,
    void* __restrict__ C, int ldc, size_t sC,
    int K, float scale, float* __restrict__ Lsum)
{
  static_assert(BN == 256 || BN == 128, "BN");
  constexpr int BM = 256;
  constexpr int BK = 64;
  constexpr int WM = (BN == 256) ? 2 : 4;
  constexpr int MI = BM / (WM * 32);        // 4 (BN=256) or 2 (BN=128)
  constexpr int NJ = BN / ((8 / WM) * 32);  // 2
  constexpr int AI = BM / 64;               // 4 stage issues for A
  constexpr int BI = BN / 64;               // 4 or 2 for B
  constexpr int ASLOT = BM * BK;            // ushorts per slot
  constexpr int BSLOT = BN * BK;

  __shared__ __align__(16) ushort As[2 * ASLOT];   // 64 KiB
  __shared__ __align__(16) ushort Bs[2 * BSLOT];   // 64 / 32 KiB

  const int tid = threadIdx.x;
  const int bz  = blockIdx.z;
  A += (size_t)bz * sA;
  B += (size_t)bz * sB;

  const int m0 = blockIdx.y * BM;
  const int n0 = blockIdx.x * BN;

  const int lane = tid & 63;
  const int w    = tid >> 6;
  const int l32  = lane & 31;
  const int lh   = lane >> 5;
  const int mw   = (BN == 256) ? (w >> 2) : (w >> 1);
  const int nw   = (BN == 256) ? (w & 3) : (w & 1);

  // ---- staging pointers: 64 rows/issue, 8 lanes x 16B per 128B row ----
  const int srow = tid >> 3;                // 0..63
  const int sch  = tid & 7;
  const ushort* agp[AI];
  const ushort* bgp[BI];
#pragma unroll
  for (int q = 0; q < AI; ++q) {
    int r = q * 64 + srow;
    agp[q] = A + (size_t)(m0 + r) * lda + ((sch ^ ((r ^ (r >> 3)) & 7)) * 8);
  }
#pragma unroll
  for (int q = 0; q < BI; ++q) {
    int r = q * 64 + srow;
    bgp[q] = B + (size_t)(n0 + r) * ldb + ((sch ^ ((r ^ (r >> 3)) & 7)) * 8);
  }

  // ---- fragment row offsets + swizzle keys (loop-invariant) ----
  int oa[MI], sa[MI], ob[NJ], sb[NJ];
#pragma unroll
  for (int i = 0; i < MI; ++i) {
    int r = mw * (MI * 32) + i * 32 + l32;
    oa[i] = r * BK; sa[i] = (r ^ (r >> 3)) & 7;
  }
#pragma unroll
  for (int j = 0; j < NJ; ++j) {
    int r = nw * (NJ * 32) + j * 32 + l32;
    ob[j] = r * BK; sb[j] = (r ^ (r >> 3)) & 7;
  }

  floatx16 acc[MI][NJ];
#pragma unroll
  for (int i = 0; i < MI; ++i)
#pragma unroll
    for (int j = 0; j < NJ; ++j)
#pragma unroll
      for (int r = 0; r < 16; ++r) acc[i][j][r] = 0.f;

  const int nt = K / BK;

#define STAGE(slot)                                                     \
  {                                                                     \
    ushort* Ad = &As[(slot) * ASLOT];                                   \
    ushort* Bd = &Bs[(slot) * BSLOT];                                   \
    _Pragma("unroll")                                                   \
    for (int q = 0; q < AI; ++q) {                                      \
      gl_lds16(agp[q], Ad + (q * 64 + w * 8) * BK); agp[q] += BK;       \
    }                                                                   \
    _Pragma("unroll")                                                   \
    for (int q = 0; q < BI; ++q) {                                      \
      gl_lds16(bgp[q], Bd + (q * 64 + w * 8) * BK); bgp[q] += BK;       \
    }                                                                   \
  }

  // prologue: stage tile 0 into slot 0 (one full drain, once)
  STAGE(0);
  __syncthreads();

  for (int t = 0; t < nt; ++t) {
    const ushort* At = &As[(t & 1) * ASLOT];
    const ushort* Bt = &Bs[(t & 1) * BSLOT];
    if (t + 1 < nt) STAGE((t + 1) & 1);     // issue early: drain at tile end
                                            // waits on ~1-tile-old loads

    short8 af[2][MI], bf[2][NJ];

#define RD(ks, buf)                                                         \
    {                                                                       \
      _Pragma("unroll")                                                     \
      for (int i = 0; i < MI; ++i)                                          \
        af[buf][i] = *(const short8*)&At[oa[i] + ((((ks)*2 + lh) ^ sa[i]) << 3)]; \
      _Pragma("unroll")                                                     \
      for (int j = 0; j < NJ; ++j)                                          \
        bf[buf][j] = *(const short8*)&Bt[ob[j] + ((((ks)*2 + lh) ^ sb[j]) << 3)]; \
    }
#define MM(buf)                                                         \
    {                                                                   \
      __builtin_amdgcn_s_setprio(1);                                    \
      _Pragma("unroll")                                                 \
      for (int i = 0; i < MI; ++i)                                      \
        _Pragma("unroll")                                               \
        for (int j = 0; j < NJ; ++j)                                    \
          acc[i][j] = __builtin_amdgcn_mfma_f32_32x32x16_bf16(          \
              af[buf][i], bf[buf][j], acc[i][j], 0, 0, 0);              \
      __builtin_amdgcn_s_setprio(0);                                    \
    }

    RD(0, 0);
    RD(1, 1);
    MM(0);        // ks0
    RD(2, 0);
    MM(1);        // ks1
    RD(3, 1);
    MM(0);        // ks2
    MM(1);        // ks3
    __syncthreads();   // vmcnt(0)+lgkmcnt(0)+barrier: tile t+1 staged & safe
#undef RD
#undef MM
  }
#undef STAGE

  // ---- epilogue; C/D (32x32): col = lane&31, row = (reg&3)+8*(reg>>2)+4*lh
  if constexpr (MODE == 0) {   // fused-QKV split
#pragma unroll
    for (int i = 0; i < MI; ++i)
#pragma unroll
      for (int j = 0; j < NJ; ++j) {
        const int mbase = m0 + mw * (MI * 32) + i * 32 + 4 * lh;
        const int ng    = n0 + nw * (NJ * 32) + j * 32 + l32;
        if (ng < 2048) {
          // Qb @ C, Kb @ C + 8M elems
          ushort* dst = (ushort*)C + (size_t)(ng >> 10) * (8u * MEG);
          const int nn = ng & 1023;
#pragma unroll
          for (int g = 0; g < 4; ++g)
#pragma unroll
            for (int r = 0; r < 4; ++r)
              dst[(size_t)(mbase + 8 * g + r) * 1024 + nn] =
                  f2b(acc[i][j][4 * g + r]);
        } else {
          // Vt @ C + 16M elems, transposed [1024][8192]
          ushort* Vo = (ushort*)C + (size_t)16 * MEG;
#pragma unroll
          for (int g = 0; g < 4; ++g) {
            uint lo = (uint)f2b(acc[i][j][4 * g + 0]) |
                      ((uint)f2b(acc[i][j][4 * g + 1]) << 16);
            uint hi = (uint)f2b(acc[i][j][4 * g + 2]) |
                      ((uint)f2b(acc[i][j][4 * g + 3]) << 16);
            *(uint2*)&Vo[(size_t)(ng - 2048) * 8192 + mbase + 8 * g] =
                make_uint2(lo, hi);
          }
        }
      }
  } else if constexpr (MODE == 1) {   // p = exp2(s*scale), row sums -> Lsum
    ushort* Cb = (ushort*)C + (size_t)bz * sC;
    float* Lb = Lsum + (size_t)bz * 2048;
    const int ng0 = n0 + nw * (NJ * 32) + l32;
#pragma unroll
    for (int i = 0; i < MI; ++i) {
      const int mbase = m0 + mw * (MI * 32) + i * 32 + 4 * lh;
#pragma unroll
      for (int g = 0; g < 4; ++g)
#pragma unroll
        for (int r = 0; r < 4; ++r) {
          const int mg = mbase + 8 * g + r;
          float p0 = exp2f(acc[i][0][4 * g + r] * scale);
          float p1 = exp2f(acc[i][NJ - 1][4 * g + r] * scale);
          ushort u0 = f2b(p0), u1 = f2b(p1);
          Cb[(size_t)mg * ldc + ng0]      = u0;
          Cb[(size_t)mg * ldc + ng0 + 32] = u1;
          float ps = b2f(u0) + b2f(u1);   // sum of *rounded* p (matches PV)
#pragma unroll
          for (int d = 1; d < 32; d <<= 1) ps += __shfl_xor(ps, d);
          if (l32 == 0) atomicAdd(&Lb[mg], ps);
        }
    }
  } else {                    // MODE 2: normalized fp32 output
    float* Cb = (float*)C + (size_t)bz * sC;
    const float* Lb = Lsum + (size_t)bz * 2048;
#pragma unroll
    for (int i = 0; i < MI; ++i) {
      const int mbase = m0 + mw * (MI * 32) + i * 32 + 4 * lh;
#pragma unroll
      for (int g = 0; g < 4; ++g)
#pragma unroll
        for (int r = 0; r < 4; ++r) {
          const int mg = mbase + 8 * g + r;
          const float inv = 1.0f / Lb[mg];
#pragma unroll
          for (int j = 0; j < NJ; ++j) {
            const int ng = n0 + nw * (NJ * 32) + j * 32 + l32;
            Cb[(size_t)mg * ldc + ng] = acc[i][j][4 * g + r] * inv;
          }
        }
    }
  }
}

// ---- distinct symbols per stage (counter attribution) ----
// (512,2): cap at 256 unified regs/wave so the block's 8 waves fit 2/SIMD.
// 1 block/CU by LDS; intra-block wave free-flow hides latency.
__global__ __launch_bounds__(512, 2) void gemm_qkv(
    const ushort* __restrict__ A, int lda, size_t sA,
    const ushort* __restrict__ B, int ldb, size_t sB,
    void* __restrict__ C, int ldc, size_t sC, int K, float scale,
    float* __restrict__ Lsum) {
  gemm_core<0, 256>(A, lda, sA, B, ldb, sB, C, ldc, sC, K, scale, Lsum);
}
__global__ __launch_bounds__(512, 2) void gemm_s(
    const ushort* __restrict__ A, int lda, size_t sA,
    const ushort* __restrict__ B, int ldb, size_t sB,
    void* __restrict__ C, int ldc, size_t sC, int K, float scale,
    float* __restrict__ Lsum) {
  gemm_core<1, 256>(A, lda, sA, B, ldb, sB, C, ldc, sC, K, scale, Lsum);
}
__global__ __launch_bounds__(512, 2) void gemm_pv(
    const ushort* __restrict__ A, int lda, size_t sA,
    const ushort* __restrict__ B, int ldb, size_t sB,
    void* __restrict__ C, int ldc, size_t sC, int K, float scale,
    float* __restrict__ Lsum) {
  gemm_core<2, 128>(A, lda, sA, B, ldb, sB, C, ldc, sC, K, scale, Lsum);
}

// ---------------------------------------------------------------------------
// ws layout (ushort elems), total 80 MiB + 32 KiB  (proven ws >= 90.2 MB):
//   Qb @ 0      [8192][1024]   (16 MiB)
//   Kb @ 8M     [8192][1024]   (16 MiB)
//   Vt @ 16M    [1024][8192]   (16 MiB)
//   xb @ 24M    [8192][1024]   (16 MiB)  -- dead after QKV
//   Wb @ 32M    [3072][1024]   ( 6 MiB)  -- dead after QKV
//   P  @ 24M    [4][2048][2048] (32 MiB) -- OVERLAYS xb+Wb (both dead)
//   Ls @ 40M    fp32 [4][2048]  (32 KiB)
// Grids (BM=256): QKV 12x32=384 blk (1.5 rounds), S 8x8x4=256 blk (1 round),
// PV (BN=128) 8x8x4=256 blk (1 round).
// ---------------------------------------------------------------------------
extern "C" void kernel_launch(void* const* d_in, const int* in_sizes, int n_in,
                              void* d_out, int out_size, void* d_ws, size_t ws_size,
                              hipStream_t stream) {
  const float* x  = (const float*)d_in[0];
  const float* Wq = (const float*)d_in[1];
  const float* Wk = (const float*)d_in[2];
  const float* Wv = (const float*)d_in[3];
  float* outp = (float*)d_out;

  const float SCALE = 1.4426950408889634f / 32.0f;   // log2(e)/sqrt(1024)

  ushort* W0 = (ushort*)d_ws;
  ushort* Qb = W0;
  ushort* Kb = W0 + (size_t)8 * MEG;
  ushort* Vt = W0 + (size_t)16 * MEG;
  ushort* xb = W0 + (size_t)24 * MEG;
  ushort* Wb = W0 + (size_t)32 * MEG;
  ushort* Pb = W0 + (size_t)24 * MEG;            // overlays xb/Wb after QKV

  const size_t NEED_FULL = ((size_t)40 * MEG) * 2 + 4 * 2048 * 4;  // 83,918,848
  const bool full = ws_size >= NEED_FULL;
  float* Ls = full ? (float*)(W0 + (size_t)40 * MEG)
                   : (float*)(W0 + (size_t)28 * MEG);  // per-batch: P is 8 MiB

  cvt_all<<<5633, 256, 0, stream>>>(x, Wq, Wk, Wv, xb, Wb, Ls);

  // fused QKV projection: [8192x1024] x [3072x1024]^T, split epilogue
  gemm_qkv<<<dim3(12, 32, 1), 512, 0, stream>>>(
      xb, 1024, 0, Wb, 1024, 0, Qb, 1024, 0, 1024, 1.f, nullptr);

  if (full) {
    gemm_s<<<dim3(8, 8, 4), 512, 0, stream>>>(
        Qb, 1024, (size_t)2048 * 1024, Kb, 1024, (size_t)2048 * 1024,
        Pb, 2048, (size_t)2048 * 2048, 1024, SCALE, Ls);
    gemm_pv<<<dim3(8, 8, 4), 512, 0, stream>>>(
        Pb, 2048, (size_t)2048 * 2048, Vt, 8192, 2048,
        outp, 1024, (size_t)2048 * 1024, 2048, 1.f, Ls);
  } else {
    // per-batch fallback (P single batch @24M, Ls @28M)
    for (int b = 0; b < 4; ++b) {
      (void)hipMemsetAsync(Ls, 0, 2048 * sizeof(float), stream);
      gemm_s<<<dim3(8, 8, 1), 512, 0, stream>>>(
          Qb + (size_t)b * 2048 * 1024, 1024, 0,
          Kb + (size_t)b * 2048 * 1024, 1024, 0,
          Pb, 2048, 0, 1024, SCALE, Ls);
      gemm_pv<<<dim3(8, 8, 1), 512, 0, stream>>>(
          Pb, 2048, 0, Vt + (size_t)b * 2048, 8192, 0,
          outp + (size_t)b * 2048 * 1024, 1024, 0, 2048, 1.f, Ls);
    }
  }
}

// Round 3
// 245.824 us; speedup vs baseline: 1.0810x; 1.0692x over previous
//
#include <hip/hip_runtime.h>
#include <stdint.h>

typedef unsigned int uint;
typedef unsigned short ushort;
typedef __attribute__((ext_vector_type(8))) short short8;
typedef __attribute__((ext_vector_type(16))) float floatx16;

#define MEG (1024u * 1024u)

// ---------- helpers ----------
__device__ inline ushort f2b(float f) {           // fp32 -> bf16 RNE
  union { float f; uint u; } c; c.f = f;
  uint u = c.u;
  u = (u + 0x7fffu + ((u >> 16) & 1u)) >> 16;
  return (ushort)u;
}
__device__ inline float b2f(ushort u) {
  union { uint i; float f; } c; c.i = ((uint)u) << 16; return c.f;
}

__device__ inline void gl_lds16(const ushort* g, ushort* l) {
  // async global->LDS, 16B/lane; LDS dest = wave-uniform base + lane*16
  __builtin_amdgcn_global_load_lds(
      (const __attribute__((address_space(1))) void*)g,
      (__attribute__((address_space(3))) void*)l, 16, 0, 0);
}

// ---------------------------------------------------------------------------
// fp32->bf16 convert (x: 4096 blocks, W: 3x512 blocks).
// (Ls zeroing removed: S now plain-stores per-block partial sums, R14.)
// ---------------------------------------------------------------------------
__global__ __launch_bounds__(256) void cvt_all(
    const float* __restrict__ x,  const float* __restrict__ wq,
    const float* __restrict__ wk, const float* __restrict__ wv,
    ushort* __restrict__ xb, ushort* __restrict__ wb)
{
  const int b = blockIdx.x;
  const float* s; ushort* d; int i;
  if (b < 4096) {
    s = x; d = xb; i = b * 256 + threadIdx.x;
  } else {
    int t = b - 4096;
    int wsel = t >> 9;
    s = (wsel == 0) ? wq : (wsel == 1) ? wk : wv;
    d = wb + (size_t)wsel * MEG;
    i = (t & 511) * 256 + threadIdx.x;
  }
  float4 a = ((const float4*)s)[i * 2];
  float4 c = ((const float4*)s)[i * 2 + 1];
  short8 v;
  v[0] = (short)f2b(a.x); v[1] = (short)f2b(a.y);
  v[2] = (short)f2b(a.z); v[3] = (short)f2b(a.w);
  v[4] = (short)f2b(c.x); v[5] = (short)f2b(c.y);
  v[6] = (short)f2b(c.z); v[7] = (short)f2b(c.w);
  ((short8*)d)[i] = v;
}

// ---------------------------------------------------------------------------
// Shared GEMM-BT core:  C[m][n] = f( sum_k A[m][k] * B[n][k] )
// 128 x BN block tile, BK=64, 256 thr = 2x2 waves, MFMA 32x32x16
// (floatx16 acc), global_load_lds width-16 staging into XOR-swizzled
// [rows][64] LDS tiles (chunk' = chunk ^ ((r^(r>>3))&7)) — kills all LDS
// bank conflicts (R5: 6.3M -> 0). No XCD swizzle (R6 regressed).
// R12/R13 256^2 single-block restructures both regressed (84.5us QKV vs
// 73.5): 1 block/CU exposes load latency + barrier convergence that the
// 3-4 block/CU 2-barrier loop hides via cross-block wave overlap (m114).
// MODE 0 (BN=128): fused-QKV split (n<2048 -> Q/K bf16 row-major, else Vt^T)
// MODE 1 (BN=128): p = exp2(s*scale) bf16 out; per-block partial row sums
//                  plain-stored to Lp[(nb*2+nw)][bz][2048]  (R14: no atomics;
//                  |s|*scale bounded ~8 so no max subtraction, fp32-safe)
// MODE 2: fp32 out, multiplied by 1/rowsum; rowsum = sum of 32 Lp partials
//         (cooperative prologue into LDS Linv[128])
// ---------------------------------------------------------------------------
template <int MODE, int BN>
__device__ __forceinline__ void gemm_core(
    const ushort* __restrict__ A, int lda, size_t sA,
    const ushort* __restrict__ B, int ldb, size_t sB,
    void* __restrict__ C, int ldc, size_t sC,
    int K, float scale, float* __restrict__ Lsum)
{
  constexpr int NJ = BN / 64;          // n-frags per wave (2 or 1)
  constexpr int NB = BN / 32;          // 32-row staging groups for B (4 or 2)
  __shared__ ushort As[128 * 64];
  __shared__ ushort Bs[BN * 64];
  __shared__ float Linv[(MODE == 2) ? 128 : 1];

  const int tid = threadIdx.x;
  const int bz  = blockIdx.z;
  A += (size_t)bz * sA;
  B += (size_t)bz * sB;

  const int m0 = blockIdx.y * 128;
  const int n0 = blockIdx.x * BN;

  const int lane = tid & 63;
  const int w    = tid >> 6;
  const int l32  = lane & 31;
  const int lh   = lane >> 5;          // 0/1 -> k-half of the 16-k step
  const int mw   = w >> 1;
  const int nw   = w & 1;

  // ---- PV prologue: reduce 32 Lp partials per row -> Linv (R14) ----
  if constexpr (MODE == 2) {
    if (tid < 128) {
      float s = 0.f;
#pragma unroll
      for (int p = 0; p < 32; ++p)
        s += Lsum[((size_t)p * gridDim.z + bz) * 2048 + m0 + tid];
      Linv[tid] = 1.0f / s;
    }
    // first __syncthreads of the K-loop publishes Linv before any use
  }

  // ---- staging pointers (32 rows per group; 8 lanes per 128B row) ----
  const int srow = tid >> 3;
  const ushort* agp[4];
  const ushort* bgp[NB];
#pragma unroll
  for (int c4 = 0; c4 < 4; ++c4) {
    int r   = c4 * 32 + srow;
    int col = (((tid & 7) ^ ((r ^ (r >> 3)) & 7))) * 8;
    agp[c4] = A + (size_t)(m0 + r) * lda + col;
  }
#pragma unroll
  for (int cb = 0; cb < NB; ++cb) {
    int r   = cb * 32 + srow;
    int col = (((tid & 7) ^ ((r ^ (r >> 3)) & 7))) * 8;
    bgp[cb] = B + (size_t)(n0 + r) * ldb + col;
  }

  // ---- fragment rows + swizzle keys (loop-invariant) ----
  int arow[2], aswz[2], brow[NJ], bswz[NJ];
#pragma unroll
  for (int t = 0; t < 2; ++t) {
    arow[t] = mw * 64 + t * 32 + l32;
    aswz[t] = (arow[t] ^ (arow[t] >> 3)) & 7;
  }
#pragma unroll
  for (int t = 0; t < NJ; ++t) {
    brow[t] = nw * (BN / 2) + t * 32 + l32;
    bswz[t] = (brow[t] ^ (brow[t] >> 3)) & 7;
  }

  floatx16 acc[2][NJ];
#pragma unroll
  for (int i = 0; i < 2; ++i)
#pragma unroll
    for (int j = 0; j < NJ; ++j)
#pragma unroll
      for (int r = 0; r < 16; ++r) acc[i][j][r] = 0.f;

  for (int k0 = 0; k0 < K; k0 += 64) {
    __syncthreads();
#pragma unroll
    for (int c4 = 0; c4 < 4; ++c4) {
      gl_lds16(agp[c4], &As[(c4 * 32 + w * 8) * 64]);
      agp[c4] += 64;
    }
#pragma unroll
    for (int cb = 0; cb < NB; ++cb) {
      gl_lds16(bgp[cb], &Bs[(cb * 32 + w * 8) * 64]);
      bgp[cb] += 64;
    }
    __syncthreads();

#pragma unroll
    for (int s = 0; s < 4; ++s) {        // 4 k-steps of 16
      short8 af[2], bf[NJ];
#pragma unroll
      for (int t = 0; t < 2; ++t)
        af[t] = *(const short8*)&As[arow[t] * 64 + (((s * 2 + lh) ^ aswz[t]) * 8)];
#pragma unroll
      for (int t = 0; t < NJ; ++t)
        bf[t] = *(const short8*)&Bs[brow[t] * 64 + (((s * 2 + lh) ^ bswz[t]) * 8)];
#pragma unroll
      for (int i = 0; i < 2; ++i)
#pragma unroll
        for (int j = 0; j < NJ; ++j)
          acc[i][j] = __builtin_amdgcn_mfma_f32_32x32x16_bf16(
              af[i], bf[j], acc[i][j], 0, 0, 0);
    }
  }

  // ---- epilogue; C/D (32x32): col = lane&31, row = (reg&3)+8*(reg>>2)+4*lh
  if constexpr (MODE == 0) {   // fused-QKV split
#pragma unroll
    for (int i = 0; i < 2; ++i)
#pragma unroll
      for (int j = 0; j < NJ; ++j) {
        const int mbase = m0 + mw * 64 + i * 32 + 4 * lh;
        const int ng    = n0 + nw * (BN / 2) + j * 32 + l32;
        if (ng < 2048) {
          // Qb @ C, Kb @ C + 8M elems
          ushort* dst = (ushort*)C + (size_t)(ng >> 10) * (8u * MEG);
          const int nn = ng & 1023;
#pragma unroll
          for (int g = 0; g < 4; ++g)
#pragma unroll
            for (int r = 0; r < 4; ++r)
              dst[(size_t)(mbase + 8 * g + r) * 1024 + nn] =
                  f2b(acc[i][j][4 * g + r]);
        } else {
          // Vt @ C + 16M elems, transposed [1024][8192]
          ushort* Vo = (ushort*)C + (size_t)16 * MEG;
#pragma unroll
          for (int g = 0; g < 4; ++g) {
            uint lo = (uint)f2b(acc[i][j][4 * g + 0]) |
                      ((uint)f2b(acc[i][j][4 * g + 1]) << 16);
            uint hi = (uint)f2b(acc[i][j][4 * g + 2]) |
                      ((uint)f2b(acc[i][j][4 * g + 3]) << 16);
            *(uint2*)&Vo[(size_t)(ng - 2048) * 8192 + mbase + 8 * g] =
                make_uint2(lo, hi);
          }
        }
      }
  } else if constexpr (MODE == 1) {   // p = exp2(s*scale), partials -> Lp
    ushort* Cb = (ushort*)C + (size_t)bz * sC;
    float* Lp = Lsum + ((size_t)(blockIdx.x * 2 + nw) * gridDim.z + bz) * 2048;
    const int ng0 = n0 + nw * (BN / 2) + l32;
#pragma unroll
    for (int i = 0; i < 2; ++i) {
      const int mbase = m0 + mw * 64 + i * 32 + 4 * lh;
#pragma unroll
      for (int g = 0; g < 4; ++g)
#pragma unroll
        for (int r = 0; r < 4; ++r) {
          const int mg = mbase + 8 * g + r;
          float p0 = exp2f(acc[i][0][4 * g + r] * scale);
          float p1 = exp2f(acc[i][NJ - 1][4 * g + r] * scale);
          ushort u0 = f2b(p0), u1 = f2b(p1);
          Cb[(size_t)mg * ldc + ng0]      = u0;
          Cb[(size_t)mg * ldc + ng0 + 32] = u1;
          float ps = b2f(u0) + b2f(u1);   // sum of *rounded* p (matches PV)
#pragma unroll
          for (int d = 1; d < 32; d <<= 1) ps += __shfl_xor(ps, d);
          if (l32 == 0) Lp[mg] = ps;      // plain store: (nb,nw) unique slot
        }
    }
  } else {                    // MODE 2: normalized fp32 output
    float* Cb = (float*)C + (size_t)bz * sC;
#pragma unroll
    for (int i = 0; i < 2; ++i) {
      const int mbase = m0 + mw * 64 + i * 32 + 4 * lh;
#pragma unroll
      for (int g = 0; g < 4; ++g)
#pragma unroll
        for (int r = 0; r < 4; ++r) {
          const int mg = mbase + 8 * g + r;
          const float inv = Linv[mg - m0];
#pragma unroll
          for (int j = 0; j < NJ; ++j) {
            const int ng = n0 + nw * (BN / 2) + j * 32 + l32;
            Cb[(size_t)mg * ldc + ng] = acc[i][j][4 * g + r] * inv;
          }
        }
    }
  }
}

// ---- distinct symbols per stage (counter attribution) ----
// (256,4): 64 VGPR + 64 AGPR = 128 unified = the 16-wave/CU boundary (m69);
// proven to fit by gemm_s in the R11 session (VGPR_Count 64 at bound 4).
// 4 blocks/CU (LDS 4x32KB=128KB) -> more cross-block overlap of the per-tile
// vmcnt drain than bound-3 (R14 edit; R12/R13 showed 1-block/CU is the enemy).
__global__ __launch_bounds__(256, 4) void gemm_qkv(
    const ushort* __restrict__ A, int lda, size_t sA,
    const ushort* __restrict__ B, int ldb, size_t sB,
    void* __restrict__ C, int ldc, size_t sC, int K, float scale,
    float* __restrict__ Lsum) {
  gemm_core<0, 128>(A, lda, sA, B, ldb, sB, C, ldc, sC, K, scale, Lsum);
}
// (256,4): S grid is exactly 1024 blocks = 4/CU x 256 CU -> whole dispatch
// resident in one round.
__global__ __launch_bounds__(256, 4) void gemm_s(
    const ushort* __restrict__ A, int lda, size_t sA,
    const ushort* __restrict__ B, int ldb, size_t sB,
    void* __restrict__ C, int ldc, size_t sC, int K, float scale,
    float* __restrict__ Lsum) {
  gemm_core<1, 128>(A, lda, sA, B, ldb, sB, C, ldc, sC, K, scale, Lsum);
}
__global__ __launch_bounds__(256, 4) void gemm_pv(
    const ushort* __restrict__ A, int lda, size_t sA,
    const ushort* __restrict__ B, int ldb, size_t sB,
    void* __restrict__ C, int ldc, size_t sC, int K, float scale,
    float* __restrict__ Lsum) {
  gemm_core<2, 128>(A, lda, sA, B, ldb, sB, C, ldc, sC, K, scale, Lsum);
}

// ---------------------------------------------------------------------------
// ws layout (ushort elems), total 81 MiB  (proven ws >= 90.2 MB):
//   Qb @ 0      [8192][1024]   (16 MiB)
//   Kb @ 8M     [8192][1024]   (16 MiB)
//   Vt @ 16M    [1024][8192]   (16 MiB)
//   xb @ 24M    [8192][1024]   (16 MiB)  -- dead after QKV
//   Wb @ 32M    [3072][1024]   ( 6 MiB)  -- dead after QKV
//   P  @ 24M    [4][2048][2048] (32 MiB) -- OVERLAYS xb+Wb (both dead)
//   Lp @ 40M    fp32 [32][4][2048] ( 1 MiB)  -- per-(nb,nw) partial row sums
// ---------------------------------------------------------------------------
extern "C" void kernel_launch(void* const* d_in, const int* in_sizes, int n_in,
                              void* d_out, int out_size, void* d_ws, size_t ws_size,
                              hipStream_t stream) {
  const float* x  = (const float*)d_in[0];
  const float* Wq = (const float*)d_in[1];
  const float* Wk = (const float*)d_in[2];
  const float* Wv = (const float*)d_in[3];
  float* outp = (float*)d_out;

  const float SCALE = 1.4426950408889634f / 32.0f;   // log2(e)/sqrt(1024)

  ushort* W0 = (ushort*)d_ws;
  ushort* Qb = W0;
  ushort* Kb = W0 + (size_t)8 * MEG;
  ushort* Vt = W0 + (size_t)16 * MEG;
  ushort* xb = W0 + (size_t)24 * MEG;
  ushort* Wb = W0 + (size_t)32 * MEG;
  ushort* Pb = W0 + (size_t)24 * MEG;            // overlays xb/Wb after QKV

  // full: P[4] (32 MiB) + Lp 32*4*2048*4B (1 MiB)
  const size_t NEED_FULL = ((size_t)40 * MEG) * 2 + (size_t)32 * 4 * 2048 * 4;
  const bool full = ws_size >= NEED_FULL;
  float* Lp = full ? (float*)(W0 + (size_t)40 * MEG)
                   : (float*)(W0 + (size_t)28 * MEG);  // per-batch: P is 8 MiB

  cvt_all<<<5632, 256, 0, stream>>>(x, Wq, Wk, Wv, xb, Wb);

  // fused QKV projection: [8192x1024] x [3072x1024]^T, split epilogue
  gemm_qkv<<<dim3(24, 64, 1), 256, 0, stream>>>(
      xb, 1024, 0, Wb, 1024, 0, Qb, 1024, 0, 1024, 1.f, nullptr);

  if (full) {
    gemm_s<<<dim3(16, 16, 4), 256, 0, stream>>>(
        Qb, 1024, (size_t)2048 * 1024, Kb, 1024, (size_t)2048 * 1024,
        Pb, 2048, (size_t)2048 * 2048, 1024, SCALE, Lp);
    gemm_pv<<<dim3(8, 16, 4), 256, 0, stream>>>(
        Pb, 2048, (size_t)2048 * 2048, Vt, 8192, 2048,
        outp, 1024, (size_t)2048 * 1024, 2048, 1.f, Lp);
  } else {
    // per-batch fallback (P single batch @24M, Lp @28M; no memset needed —
    // every Lp slot is plain-stored exactly once per S launch)
    for (int b = 0; b < 4; ++b) {
      gemm_s<<<dim3(16, 16, 1), 256, 0, stream>>>(
          Qb + (size_t)b * 2048 * 1024, 1024, 0,
          Kb + (size_t)b * 2048 * 1024, 1024, 0,
          Pb, 2048, 0, 1024, SCALE, Lp);
      gemm_pv<<<dim3(8, 16, 1), 256, 0, stream>>>(
          Pb, 2048, 0, Vt + (size_t)b * 2048, 8192, 0,
          outp + (size_t)b * 2048 * 1024, 1024, 0, 2048, 1.f, Lp);
    }
  }
}